// Round 1
// baseline (5839.846 us; speedup 1.0000x reference)
//
#include <hip/hip_runtime.h>

// Problem constants
#define B_ 16
#define C_ 256
#define T_ 2048
#define K_ 8192
#define D_ 256
#define N_ (B_ * T_)                 // 32768 rows
#define ROWS 16                      // rows per argmin block
#define OUTQ ((size_t)B_ * C_ * T_)  // 8388608 quantized elements

// ---------------------------------------------------------------------------
// Kernel 1: argmin over K codes per row, faithfully emulating the reference's
// fp32 rounding:
//   dist = fl( fl(x2 + e2) - fl(2*mm) ), argmin with first-index tie-break.
// x2, e2: sequential fp32 sums of separately-rounded squares (XLA-CPU order).
// mm: fp64 accumulation (error ~1e-16 abs, far below the 1.5e-5 bin width).
// ---------------------------------------------------------------------------
__global__ __launch_bounds__(256) void vq_argmin_kernel(
    const float* __restrict__ lat, const float* __restrict__ emb,
    int* __restrict__ idx_out)
{
  __shared__ float xs[ROWS][260];              // +4 pad: 16B-aligned rows, no conflicts
  __shared__ float x2s[ROWS];
  __shared__ unsigned long long red[256];

  const int tid = threadIdx.x;
  const int n0  = blockIdx.x * ROWS;           // first row of this block
  const int b   = n0 >> 11;                    // n = b*2048 + t
  const int t0  = n0 & (T_ - 1);

  // Stage 16 rows: xs[r][c] = lat[b][c][t0+r]  (coalesced 64B segments)
  for (int p = 0; p < 16; ++p) {
    int c = p * 16 + (tid >> 4);
    int r = tid & 15;
    xs[r][c] = lat[((size_t)b * C_ + c) * T_ + (t0 + r)];
  }
  __syncthreads();

  // x2 per row: strictly sequential fp32, squares rounded separately
  if (tid < ROWS) {
    #pragma clang fp contract(off)
    float s = 0.f;
    for (int c = 0; c < 256; ++c) { float v = xs[tid][c]; float sq = v * v; s = s + sq; }
    x2s[tid] = s;
  }
  __syncthreads();

  float x2r[ROWS];
  for (int r = 0; r < ROWS; ++r) x2r[r] = x2s[r];

  unsigned long long best[ROWS];
  for (int r = 0; r < ROWS; ++r) best[r] = ~0ull;

  // Each thread owns codes kk = tid, tid+256, ... (ascending -> per-thread
  // first-index semantics; cross-thread handled by packed (dist,k) min).
  for (int kk = tid; kk < K_; kk += 256) {
    const float* e = emb + (size_t)kk * D_;
    float e2 = 0.f;
    double acc[ROWS];
    for (int r = 0; r < ROWS; ++r) acc[r] = 0.0;
    {
      #pragma clang fp contract(off)
      for (int d4 = 0; d4 < 64; ++d4) {
        const float4 ev = *reinterpret_cast<const float4*>(e + d4 * 4);
        float s0 = ev.x * ev.x; e2 = e2 + s0;       // sequential fp32 e2
        float s1 = ev.y * ev.y; e2 = e2 + s1;
        float s2 = ev.z * ev.z; e2 = e2 + s2;
        float s3 = ev.w * ev.w; e2 = e2 + s3;
        for (int r = 0; r < ROWS; ++r) {
          const float4 xv = *reinterpret_cast<const float4*>(&xs[r][d4 * 4]);
          acc[r] = fma((double)xv.x, (double)ev.x, acc[r]);
          acc[r] = fma((double)xv.y, (double)ev.y, acc[r]);
          acc[r] = fma((double)xv.z, (double)ev.z, acc[r]);
          acc[r] = fma((double)xv.w, (double)ev.w, acc[r]);
        }
      }
    }
    {
      #pragma clang fp contract(off)
      for (int r = 0; r < ROWS; ++r) {
        float mmf  = (float)acc[r];          // matmul result rounded to fp32
        float tk   = x2r[r] + e2;            // fl(x2 + e2)
        float two  = 2.0f * mmf;             // exact
        float dist = tk - two;               // final fp32 rounding at ~256
        unsigned long long packed =
            ((unsigned long long)__float_as_uint(dist) << 32) | (unsigned int)kk;
        if (packed < best[r]) best[r] = packed;   // dist>0 -> bits are ordered
      }
    }
  }

  // Block reduction per row: lexicographic min of (dist_bits, k)
  for (int r = 0; r < ROWS; ++r) {
    __syncthreads();
    red[tid] = best[r];
    __syncthreads();
    for (int s = 128; s > 0; s >>= 1) {
      if (tid < s) {
        unsigned long long o = red[tid + s];
        if (o < red[tid]) red[tid] = o;
      }
      __syncthreads();
    }
    if (tid == 0) idx_out[n0 + r] = (int)(red[0] & 0xffffffffu);
  }
}

// ---------------------------------------------------------------------------
// Kernel 2: quantized output (gather, [B,C,T] layout) + fp64 loss partials
// ---------------------------------------------------------------------------
__global__ __launch_bounds__(256) void vq_out_kernel(
    const float* __restrict__ lat, const float* __restrict__ emb,
    const int* __restrict__ idx, float* __restrict__ outq,
    double* __restrict__ partial)
{
  __shared__ double sred[256];
  int gid = blockIdx.x;                 // 0..32767 = b(16) x c(256) x tchunk(8)
  int b   = gid >> 11;
  int rem = gid & 2047;
  int c   = rem >> 3;
  int tc  = rem & 7;
  int t   = tc * 256 + threadIdx.x;

  size_t off = ((size_t)b * C_ + c) * T_ + t;
  float l = lat[off];
  int   n = idx[b * T_ + t];
  float q = emb[(size_t)n * D_ + c];
  outq[off] = q;

  double d = (double)q - (double)l;
  sred[threadIdx.x] = d * d;
  __syncthreads();
  for (int s = 128; s > 0; s >>= 1) {
    if (threadIdx.x < s) sred[threadIdx.x] += sred[threadIdx.x + s];
    __syncthreads();
  }
  if (threadIdx.x == 0) partial[gid] = sred[0];
}

// ---------------------------------------------------------------------------
// Kernel 3: finalize loss = m + 0.25*m,  m = mean((q - lat)^2)
// ---------------------------------------------------------------------------
__global__ __launch_bounds__(256) void vq_loss_kernel(
    const double* __restrict__ partial, float* __restrict__ out_loss)
{
  __shared__ double sred[256];
  double s = 0.0;
  for (int i = threadIdx.x; i < 32768; i += 256) s += partial[i];
  sred[threadIdx.x] = s;
  __syncthreads();
  for (int st = 128; st > 0; st >>= 1) {
    if (threadIdx.x < st) sred[threadIdx.x] += sred[threadIdx.x + st];
    __syncthreads();
  }
  if (threadIdx.x == 0) {
    double m = sred[0] / (double)OUTQ;
    out_loss[0] = (float)(m + 0.25 * m);
  }
}

// ---------------------------------------------------------------------------
// Kernel 4: idx -> float tail of d_out
// ---------------------------------------------------------------------------
__global__ __launch_bounds__(256) void vq_idxcopy_kernel(
    const int* __restrict__ idx, float* __restrict__ outi)
{
  int i = blockIdx.x * 256 + threadIdx.x;
  if (i < N_) outi[i] = (float)idx[i];
}

extern "C" void kernel_launch(void* const* d_in, const int* in_sizes, int n_in,
                              void* d_out, int out_size, void* d_ws, size_t ws_size,
                              hipStream_t stream)
{
  const float* lat = (const float*)d_in[0];   // [B, C, T] fp32
  const float* emb = (const float*)d_in[1];   // [K, D] fp32

  float* outq     = (float*)d_out;            // [B, C, T]
  float* out_loss = outq + OUTQ;              // scalar
  float* out_idx  = outq + OUTQ + 1;          // [B, T] as float

  // workspace: 32768 fp64 loss partials (256KB) then 32768 int idx (128KB)
  double* partial = (double*)d_ws;
  int*    idx     = (int*)((char*)d_ws + 32768 * sizeof(double));

  vq_argmin_kernel <<<N_ / ROWS, 256, 0, stream>>>(lat, emb, idx);
  vq_out_kernel    <<<32768,     256, 0, stream>>>(lat, emb, idx, outq, partial);
  vq_loss_kernel   <<<1,         256, 0, stream>>>(partial, out_loss);
  vq_idxcopy_kernel<<<N_ / 256,  256, 0, stream>>>(idx, out_idx);
}

// Round 2
// 4360.385 us; speedup vs baseline: 1.3393x; 1.3393x over previous
//
#include <hip/hip_runtime.h>

// Problem constants
#define B_ 16
#define C_ 256
#define T_ 2048
#define K_ 8192
#define D_ 256
#define N_ (B_ * T_)                 // 32768 rows
#define ROWS 16                      // rows per argmin block
#define OUTQ ((size_t)B_ * C_ * T_)  // 8388608 quantized elements

// Phase-1 candidate margin in mm units. Required: bin/2 (1.53e-5) + 2*pack
// quantization (3e-5) + fp32 GEMM err (~1e-8) + e2 variation (~5e-7) ≈ 4.7e-5.
#define MARGIN 1e-4f
// Bias to make y = mm + BIAS positive in a narrow exponent band (mm: |mm|<~7e-3)
#define BIAS 0.015625f

__device__ __forceinline__ unsigned int umin_(unsigned int a, unsigned int b){ return a<b?a:b; }
__device__ __forceinline__ unsigned int umax_(unsigned int a, unsigned int b){ return a>b?a:b; }

// ---------------------------------------------------------------------------
// Kernel 1: argmin over K codes per row.
// Phase 1 (fast): fp32 GEMM mm = x·e, per-(thread,row) top-2 of packed
//   (quantized_mm[19b] | k[13b]) uints. e2/x2 play no role at this margin.
// Phase 2 (exact): for candidates within MARGIN of the row max, emulate the
//   reference's fp32 rounding exactly:
//   dist = fl( fl(x2 + e2) - fl(2*fl32(mm_f64)) ), sequential-fp32 x2/e2,
//   argmin + first-index tie-break via packed (dist_bits<<32|k) atomicMin.
// ---------------------------------------------------------------------------
__global__ __launch_bounds__(256, 2) void vq_argmin_kernel(
    const float* __restrict__ lat, const float* __restrict__ emb,
    int* __restrict__ idx_out)
{
  __shared__ float xs[ROWS][260];               // 16 rows x 256 (pad 4)
  __shared__ float x2s[ROWS];
  __shared__ unsigned int Lm[ROWS][256];        // per-thread row maxima
  __shared__ float rowmax_f[ROWS];
  __shared__ unsigned long long bestp[ROWS];

  const int tid = threadIdx.x;
  const int n0  = blockIdx.x * ROWS;
  const int b   = n0 >> 11;
  const int t0  = n0 & (T_ - 1);

  // Stage 16 rows: xs[r][c] = lat[b][c][t0+r]
  for (int p = 0; p < 16; ++p) {
    int c = p * 16 + (tid >> 4);
    int r = tid & 15;
    xs[r][c] = lat[((size_t)b * C_ + c) * T_ + (t0 + r)];
  }
  if (tid < ROWS) bestp[tid] = ~0ull;
  __syncthreads();

  // x2 per row: strictly sequential fp32, squares rounded separately
  if (tid < ROWS) {
    #pragma clang fp contract(off)
    float s = 0.f;
    for (int c = 0; c < 256; ++c) { float v = xs[tid][c]; float sq = v * v; s = s + sq; }
    x2s[tid] = s;
  }
  __syncthreads();

  // ---------------- Phase 1: fp32 GEMM + per-thread top-2 ----------------
  unsigned int m1[ROWS], m2[ROWS];
  #pragma unroll
  for (int r = 0; r < ROWS; ++r) { m1[r] = 0u; m2[r] = 0u; }

  for (int q = 0; q < 8; ++q) {
    const int k0 = q * 1024 + tid * 4;          // this thread's 4 codes
    const float* __restrict__ e0 = emb + (size_t)k0 * D_;

    float acc[ROWS][4];
    #pragma unroll
    for (int r = 0; r < ROWS; ++r)
      { acc[r][0]=0.f; acc[r][1]=0.f; acc[r][2]=0.f; acc[r][3]=0.f; }

    for (int d4 = 0; d4 < 64; ++d4) {
      const float4 ev0 = *reinterpret_cast<const float4*>(e0 +           d4 * 4);
      const float4 ev1 = *reinterpret_cast<const float4*>(e0 +     D_ +  d4 * 4);
      const float4 ev2 = *reinterpret_cast<const float4*>(e0 + 2 * D_ +  d4 * 4);
      const float4 ev3 = *reinterpret_cast<const float4*>(e0 + 3 * D_ +  d4 * 4);
      #pragma unroll
      for (int r = 0; r < ROWS; ++r) {
        const float4 xv = *reinterpret_cast<const float4*>(&xs[r][d4 * 4]);
        acc[r][0] = fmaf(xv.x, ev0.x, acc[r][0]);
        acc[r][0] = fmaf(xv.y, ev0.y, acc[r][0]);
        acc[r][0] = fmaf(xv.z, ev0.z, acc[r][0]);
        acc[r][0] = fmaf(xv.w, ev0.w, acc[r][0]);
        acc[r][1] = fmaf(xv.x, ev1.x, acc[r][1]);
        acc[r][1] = fmaf(xv.y, ev1.y, acc[r][1]);
        acc[r][1] = fmaf(xv.z, ev1.z, acc[r][1]);
        acc[r][1] = fmaf(xv.w, ev1.w, acc[r][1]);
        acc[r][2] = fmaf(xv.x, ev2.x, acc[r][2]);
        acc[r][2] = fmaf(xv.y, ev2.y, acc[r][2]);
        acc[r][2] = fmaf(xv.z, ev2.z, acc[r][2]);
        acc[r][2] = fmaf(xv.w, ev2.w, acc[r][2]);
        acc[r][3] = fmaf(xv.x, ev3.x, acc[r][3]);
        acc[r][3] = fmaf(xv.y, ev3.y, acc[r][3]);
        acc[r][3] = fmaf(xv.z, ev3.z, acc[r][3]);
        acc[r][3] = fmaf(xv.w, ev3.w, acc[r][3]);
      }
    }

    // top-2 update with packed (quantized value | code) uints
    #pragma unroll
    for (int r = 0; r < ROWS; ++r) {
      #pragma unroll
      for (int c = 0; c < 4; ++c) {
        const unsigned int p =
            (__float_as_uint(acc[r][c] + BIAS) & 0xFFFFE000u) | (unsigned int)(k0 + c);
        const unsigned int mn = umin_(p, m1[r]);
        m1[r] = umax_(p, m1[r]);
        m2[r] = umax_(m2[r], mn);
      }
    }
  }

  // ---------------- row max across the block ----------------
  #pragma unroll
  for (int r = 0; r < ROWS; ++r) Lm[r][tid] = m1[r];
  __syncthreads();
  {
    const int w = tid >> 6, lane = tid & 63;    // 4 waves x 4 rows
    for (int rr = 0; rr < 4; ++rr) {
      const int r = w * 4 + rr;
      unsigned int v = umax_(umax_(Lm[r][lane], Lm[r][lane + 64]),
                             umax_(Lm[r][lane + 128], Lm[r][lane + 192]));
      for (int s = 32; s > 0; s >>= 1) v = umax_(v, __shfl_xor(v, s));
      if (lane == 0)
        rowmax_f[r] = __uint_as_float(v & 0xFFFFE000u) - BIAS;
    }
  }
  __syncthreads();

  // ---------------- Phase 2: exact refinement of candidates ----------------
  for (int r = 0; r < ROWS; ++r) {
    const float thr = rowmax_f[r] - MARGIN;
    #pragma unroll
    for (int which = 0; which < 2; ++which) {
      const unsigned int p = which ? m2[r] : m1[r];
      const float val = __uint_as_float(p & 0xFFFFE000u) - BIAS;
      if (val >= thr) {
        const int k = (int)(p & 8191u);
        const float* __restrict__ e = emb + (size_t)k * D_;
        float e2 = 0.f;
        double a0 = 0.0, a1 = 0.0, a2 = 0.0, a3 = 0.0;
        {
          #pragma clang fp contract(off)
          for (int d4 = 0; d4 < 64; ++d4) {
            const float4 ev = *reinterpret_cast<const float4*>(e + d4 * 4);
            float s0 = ev.x * ev.x; e2 = e2 + s0;   // sequential fp32 e2
            float s1 = ev.y * ev.y; e2 = e2 + s1;
            float s2 = ev.z * ev.z; e2 = e2 + s2;
            float s3 = ev.w * ev.w; e2 = e2 + s3;
            const float4 xv = *reinterpret_cast<const float4*>(&xs[r][d4 * 4]);
            a0 = fma((double)xv.x, (double)ev.x, a0);
            a1 = fma((double)xv.y, (double)ev.y, a1);
            a2 = fma((double)xv.z, (double)ev.z, a2);
            a3 = fma((double)xv.w, (double)ev.w, a3);
          }
        }
        const float mmf = (float)((a0 + a1) + (a2 + a3));
        float dist;
        {
          #pragma clang fp contract(off)
          const float tk  = x2s[r] + e2;     // fl(x2 + e2)
          const float two = 2.0f * mmf;      // exact
          dist = tk - two;                   // final fp32 rounding
        }
        const unsigned long long pk =
            ((unsigned long long)__float_as_uint(dist) << 32) | (unsigned int)k;
        atomicMin(&bestp[r], pk);
      }
    }
  }
  __syncthreads();
  if (tid < ROWS) idx_out[n0 + tid] = (int)(bestp[tid] & 0xFFFFFFFFu);
}

// ---------------------------------------------------------------------------
// Kernel 2: quantized output (gather, [B,C,T] layout) + fp64 loss partials
// ---------------------------------------------------------------------------
__global__ __launch_bounds__(256) void vq_out_kernel(
    const float* __restrict__ lat, const float* __restrict__ emb,
    const int* __restrict__ idx, float* __restrict__ outq,
    double* __restrict__ partial)
{
  __shared__ double sred[256];
  int gid = blockIdx.x;                 // 0..32767 = b(16) x c(256) x tchunk(8)
  int b   = gid >> 11;
  int rem = gid & 2047;
  int c   = rem >> 3;
  int tc  = rem & 7;
  int t   = tc * 256 + threadIdx.x;

  size_t off = ((size_t)b * C_ + c) * T_ + t;
  float l = lat[off];
  int   n = idx[b * T_ + t];
  float q = emb[(size_t)n * D_ + c];
  outq[off] = q;

  double d = (double)q - (double)l;
  sred[threadIdx.x] = d * d;
  __syncthreads();
  for (int s = 128; s > 0; s >>= 1) {
    if (threadIdx.x < s) sred[threadIdx.x] += sred[threadIdx.x + s];
    __syncthreads();
  }
  if (threadIdx.x == 0) partial[gid] = sred[0];
}

// ---------------------------------------------------------------------------
// Kernel 3: finalize loss = m + 0.25*m,  m = mean((q - lat)^2)
// ---------------------------------------------------------------------------
__global__ __launch_bounds__(256) void vq_loss_kernel(
    const double* __restrict__ partial, float* __restrict__ out_loss)
{
  __shared__ double sred[256];
  double s = 0.0;
  for (int i = threadIdx.x; i < 32768; i += 256) s += partial[i];
  sred[threadIdx.x] = s;
  __syncthreads();
  for (int st = 128; st > 0; st >>= 1) {
    if (threadIdx.x < st) sred[threadIdx.x] += sred[threadIdx.x + st];
    __syncthreads();
  }
  if (threadIdx.x == 0) {
    double m = sred[0] / (double)OUTQ;
    out_loss[0] = (float)(m + 0.25 * m);
  }
}

// ---------------------------------------------------------------------------
// Kernel 4: idx -> float tail of d_out
// ---------------------------------------------------------------------------
__global__ __launch_bounds__(256) void vq_idxcopy_kernel(
    const int* __restrict__ idx, float* __restrict__ outi)
{
  int i = blockIdx.x * 256 + threadIdx.x;
  if (i < N_) outi[i] = (float)idx[i];
}

extern "C" void kernel_launch(void* const* d_in, const int* in_sizes, int n_in,
                              void* d_out, int out_size, void* d_ws, size_t ws_size,
                              hipStream_t stream)
{
  const float* lat = (const float*)d_in[0];   // [B, C, T] fp32
  const float* emb = (const float*)d_in[1];   // [K, D] fp32

  float* outq     = (float*)d_out;            // [B, C, T]
  float* out_loss = outq + OUTQ;              // scalar
  float* out_idx  = outq + OUTQ + 1;          // [B, T] as float

  double* partial = (double*)d_ws;
  int*    idx     = (int*)((char*)d_ws + 32768 * sizeof(double));

  vq_argmin_kernel <<<N_ / ROWS, 256, 0, stream>>>(lat, emb, idx);
  vq_out_kernel    <<<32768,     256, 0, stream>>>(lat, emb, idx, outq, partial);
  vq_loss_kernel   <<<1,         256, 0, stream>>>(partial, out_loss);
  vq_idxcopy_kernel<<<N_ / 256,  256, 0, stream>>>(idx, out_idx);
}

// Round 4
// 371.886 us; speedup vs baseline: 15.7033x; 11.7251x over previous
//
#include <hip/hip_runtime.h>

// Problem constants
#define B_ 16
#define C_ 256
#define T_ 2048
#define K_ 8192
#define D_ 256
#define N_ (B_ * T_)                 // 32768 rows
#define OUTQ ((size_t)B_ * C_ * T_)  // 8388608 quantized elements

#define BM 128                       // rows per argmin block
#define CHUNK 64                     // codes per LDS chunk
#define NCHUNK (K_ / CHUNK)          // 128
// Phase-1 margin (biased-mm units). Worst-case bf16 2*2^-9*||x||*||e|| <=1.77e-4
// + pack quant 6.1e-5 + fp32 bin slack 3.2e-5 = 2.7e-4 < 4e-4.
#define MARGINF 4e-4f
#define BIASF 0.03125f               // 2^-5, folded into MFMA acc init
#define QCAP 1024

typedef __attribute__((ext_vector_type(8))) short bf16x8;   // 8 bf16 = 4 VGPR
typedef __attribute__((ext_vector_type(4))) float f32x4;

__device__ __forceinline__ unsigned f2bf(float f) {         // RTNE f32->bf16
  unsigned u = __float_as_uint(f);
  return (u + 0x7FFFu + ((u >> 16) & 1u)) >> 16;
}
__device__ __forceinline__ unsigned umin_(unsigned a, unsigned b){return a<b?a:b;}
__device__ __forceinline__ unsigned umax_(unsigned a, unsigned b){return a>b?a:b;}

#define GLDS(g, l) __builtin_amdgcn_global_load_lds( \
    (const __attribute__((address_space(1))) void*)(g), \
    (__attribute__((address_space(3))) void*)(l), 16, 0, 0)

// ---------------------------------------------------------------------------
// Prep: E fp32 -> bf16, XOR-16 swizzle PRE-APPLIED in global memory so that
// global_load_lds (linear) lands it swizzled in LDS (T2 both-sides rule).
// Element (code,d) bf16 stored at byte: code*512 + ((2d) ^ ((code&15)<<4)).
// ---------------------------------------------------------------------------
__global__ __launch_bounds__(256) void ebf_prep_kernel(
    const float* __restrict__ emb, unsigned char* __restrict__ ebf)
{
  int gid  = blockIdx.x * 256 + threadIdx.x;    // 8192 codes x 64 quads
  int code = gid >> 6, dq = gid & 63;
  float4 v = *reinterpret_cast<const float4*>(emb + (size_t)code * D_ + dq * 4);
  unsigned lo = f2bf(v.x) | (f2bf(v.y) << 16);
  unsigned hi = f2bf(v.z) | (f2bf(v.w) << 16);
  unsigned off = code * 512 + ((dq * 8) ^ ((code & 15) << 4));
  *reinterpret_cast<uint2*>(ebf + off) = make_uint2(lo, hi);
}

// ---------------------------------------------------------------------------
// Argmin: phase 1 = bf16 MFMA GEMM (A=X rows in registers, B=E chunks via
// swizzled global_load_lds dbuf), per-(lane,row-slot) top-2 of packed
// (quantized mm+BIAS | k). Phase 2 = exact fp32-rounding-emulated refine of
// all candidates within MARGINF of the row max, via load-balanced worklist.
// ---------------------------------------------------------------------------
__global__ __launch_bounds__(256, 1) void vq_argmin_kernel(
    const float* __restrict__ lat, const float* __restrict__ emb,
    const unsigned char* __restrict__ ebf, int* __restrict__ idx_out)
{
  __shared__ __align__(16) unsigned char Ebuf[2][CHUNK * 512];  // 64KB dbuf
  __shared__ unsigned rmaxU[2][BM];
  __shared__ unsigned long long bestp[BM];
  __shared__ unsigned qlist[QCAP];
  __shared__ int qn;

  const int tid  = threadIdx.x;
  const int lane = tid & 63;
  const int w    = tid >> 6;       // wave 0..3
  const int rg   = w >> 1;         // row group (64 rows)
  const int cg   = w & 1;          // code group (32 codes)
  const int kg   = lane >> 4;      // k-group 0..3 (16x16x32 A/B k map)
  const int l15  = lane & 15;

  const int n0    = blockIdx.x * BM;
  const int bb    = n0 >> 11;                  // batch (BM | 2048)
  const int tbase = n0 & (T_ - 1);
  const float* latb = lat + (size_t)bb * C_ * T_;

  if (tid == 0) qn = 0;
  if (tid < BM) bestp[tid] = ~0ull;

  // prefetch chunk 0 (each wave DMAs its 8KB quarter; lane*16 on SOURCE only)
  {
    const unsigned char* src = ebf + w * 8192 + lane * 16;
    unsigned char* dst = &Ebuf[0][w * 8192];
    #pragma unroll
    for (int j = 0; j < 8; ++j) GLDS(src + j * 1024, dst + j * 1024);
  }

  // ---- A fragments: 64 rows x 256 dims bf16, resident (128 VGPR) ----
  // A map: row = lane&15 (+rf*16+rg*64), k = (lane>>4)*8 + j (+ks*32)
  bf16x8 A[4][8];
  #pragma unroll
  for (int rf = 0; rf < 4; ++rf) {
    const int t = tbase + rg * 64 + rf * 16 + l15;
    const float* lp = latb + t;
    #pragma unroll
    for (int ks = 0; ks < 8; ++ks) {
      const int c0 = ks * 32 + kg * 8;
      bf16x8 a;
      #pragma unroll
      for (int j = 0; j < 8; ++j)
        a[j] = (short)f2bf(lp[(size_t)(c0 + j) * T_]);   // coalesced across l15
      A[rf][ks] = a;
    }
  }
  __syncthreads();   // drains chunk-0 DMA (syncthreads waits vmcnt 0)

  unsigned m1[16], m2[16];
  #pragma unroll
  for (int s = 0; s < 16; ++s) { m1[s] = 0u; m2[s] = 0u; }
  const unsigned kv0 = cg * 32 + l15;

  for (int ch = 0; ch < NCHUNK; ++ch) {
    const int pb = ch & 1;
    if (ch + 1 < NCHUNK) {       // prefetch next chunk into other buffer
      const unsigned char* src =
          ebf + (size_t)(ch + 1) * (CHUNK * 512) + w * 8192 + lane * 16;
      unsigned char* dst = &Ebuf[pb ^ 1][w * 8192];
      #pragma unroll
      for (int j = 0; j < 8; ++j) GLDS(src + j * 1024, dst + j * 1024);
    }

    // B fragments: col = lane&15, k = (lane>>4)*8+j — swizzled, conflict-free
    bf16x8 Bf[2][8];
    const unsigned char* bbase = &Ebuf[pb][0];
    #pragma unroll
    for (int cf = 0; cf < 2; ++cf) {
      const int code_l = cg * 32 + cf * 16 + l15;
      #pragma unroll
      for (int ks = 0; ks < 8; ++ks) {
        const unsigned off = code_l * 512 + ((ks * 64 + kg * 16) ^ (l15 << 4));
        Bf[cf][ks] = *reinterpret_cast<const bf16x8*>(bbase + off);
      }
    }

    #pragma unroll
    for (int cf = 0; cf < 2; ++cf) {
      const unsigned kv = kv0 + (unsigned)(ch * 64 + cf * 16);
      #pragma unroll
      for (int rf = 0; rf < 4; ++rf) {
        f32x4 acc = {BIASF, BIASF, BIASF, BIASF};   // BIAS folded into C-init
        #pragma unroll
        for (int ks = 0; ks < 8; ++ks)
          acc = __builtin_amdgcn_mfma_f32_16x16x32_bf16(A[rf][ks], Bf[cf][ks],
                                                        acc, 0, 0, 0);
        #pragma unroll
        for (int r = 0; r < 4; ++r) {   // C: col=lane&15, row=(lane>>4)*4+r
          const unsigned p = (__float_as_uint(acc[r]) & 0xFFFFE000u) | kv;
          const int s = rf * 4 + r;
          const unsigned mn = umin_(p, m1[s]);
          m1[s] = umax_(p, m1[s]);
          m2[s] = umax_(m2[s], mn);
        }
      }
    }
    __syncthreads();   // drain DMA(ch+1), release Ebuf[pb]
  }

  // ---- row max: reduce over lane&15 (16 lanes hold same row set) ----
  #pragma unroll
  for (int s = 0; s < 16; ++s) {
    unsigned v = m1[s];
    v = umax_(v, __shfl_xor(v, 1));
    v = umax_(v, __shfl_xor(v, 2));
    v = umax_(v, __shfl_xor(v, 4));
    v = umax_(v, __shfl_xor(v, 8));
    const int row = rg * 64 + (s >> 2) * 16 + kg * 4 + (s & 3);
    rmaxU[cg][row] = v;                 // 16 lanes write same value: benign
  }
  __syncthreads();

  // ---- candidate emission (load-balanced worklist) ----
  #pragma unroll
  for (int s = 0; s < 16; ++s) {
    const int row = rg * 64 + (s >> 2) * 16 + kg * 4 + (s & 3);
    const unsigned rm = umax_(rmaxU[0][row], rmaxU[1][row]);
    const float thr = __uint_as_float(rm & 0xFFFFE000u) - MARGINF;
    #pragma unroll
    for (int which = 0; which < 2; ++which) {
      const unsigned m = which ? m2[s] : m1[s];
      if (__uint_as_float(m & 0xFFFFE000u) >= thr) {
        int id = atomicAdd(&qn, 1);
        if (id < QCAP) qlist[id] = ((unsigned)row << 13) | (m & 0x1FFFu);
      }
    }
  }
  __syncthreads();

  // ---- phase 2: exact refine, one candidate per lane ----
  const int nq = qn < QCAP ? qn : QCAP;
  for (int i = tid; i < nq; i += 256) {
    const unsigned e = qlist[i];
    const int row = (int)(e >> 13);
    const int k   = (int)(e & 0x1FFFu);
    const int t   = tbase + row;
    const float* xp = latb + t;
    const float* ep = emb + (size_t)k * D_;
    float x2 = 0.f, e2 = 0.f;
    double da = 0.0;
    {
      #pragma clang fp contract(off)
      for (int c = 0; c < D_; ++c) {
        const float xv = xp[(size_t)c * T_];
        const float ev = ep[c];
        const float xs = xv * xv; x2 = x2 + xs;   // sequential fp32, ref order
        const float es = ev * ev; e2 = e2 + es;
        da = fma((double)xv, (double)ev, da);
      }
    }
    float dist;
    {
      #pragma clang fp contract(off)
      const float mmf = (float)da;     // mm rounded to fp32
      const float tk  = x2 + e2;       // fl(x2 + e2)
      const float two = 2.0f * mmf;    // exact
      dist = tk - two;                 // final fp32 rounding
    }
    const unsigned long long pk =
        ((unsigned long long)__float_as_uint(dist) << 32) | (unsigned)k;
    atomicMin(&bestp[row], pk);        // first-index tie-break via low bits
  }
  __syncthreads();
  if (tid < BM) idx_out[n0 + tid] = (int)(bestp[tid] & 0xFFFFFFFFu);
}

// ---------------------------------------------------------------------------
// Output gather + loss partials. Block = (b, 64-t chunk); emb gathered by
// row (cache-line efficient), lat/outq fully coalesced over t.
// ---------------------------------------------------------------------------
__global__ __launch_bounds__(256) void vq_out_kernel(
    const float* __restrict__ lat, const float* __restrict__ emb,
    const int* __restrict__ idx, float* __restrict__ outq,
    double* __restrict__ partial)
{
  __shared__ double sred[256];
  const int gid = blockIdx.x;          // b(16) x tc(32)
  const int b   = gid >> 5;
  const int t0  = (gid & 31) * 64;
  const int tl  = threadIdx.x & 63;
  const int cq  = threadIdx.x >> 6;
  const int t   = t0 + tl;
  const int n   = idx[b * T_ + t];
  const float* ep = emb + (size_t)n * D_;
  double lsum = 0.0;
  for (int ci = 0; ci < 64; ++ci) {
    const int c = cq * 64 + ci;
    const size_t off = ((size_t)b * C_ + c) * T_ + t;
    const float q = ep[c];
    const float l = lat[off];
    outq[off] = q;
    const double d = (double)q - (double)l;
    lsum += d * d;
  }
  sred[threadIdx.x] = lsum;
  __syncthreads();
  for (int s = 128; s > 0; s >>= 1) {
    if (threadIdx.x < s) sred[threadIdx.x] += sred[threadIdx.x + s];
    __syncthreads();
  }
  if (threadIdx.x == 0) partial[gid] = sred[0];
}

__global__ __launch_bounds__(256) void vq_loss_kernel(
    const double* __restrict__ partial, float* __restrict__ out_loss)
{
  __shared__ double sred[256];
  double s = 0.0;
  for (int i = threadIdx.x; i < 512; i += 256) s += partial[i];
  sred[threadIdx.x] = s;
  __syncthreads();
  for (int st = 128; st > 0; st >>= 1) {
    if (threadIdx.x < st) sred[threadIdx.x] += sred[threadIdx.x + st];
    __syncthreads();
  }
  if (threadIdx.x == 0) {
    double m = sred[0] / (double)OUTQ;
    out_loss[0] = (float)(m + 0.25 * m);
  }
}

__global__ __launch_bounds__(256) void vq_idxcopy_kernel(
    const int* __restrict__ idx, float* __restrict__ outi)
{
  int i = blockIdx.x * 256 + threadIdx.x;
  if (i < N_) outi[i] = (float)idx[i];
}

extern "C" void kernel_launch(void* const* d_in, const int* in_sizes, int n_in,
                              void* d_out, int out_size, void* d_ws, size_t ws_size,
                              hipStream_t stream)
{
  const float* lat = (const float*)d_in[0];   // [B, C, T] fp32
  const float* emb = (const float*)d_in[1];   // [K, D] fp32

  float* outq     = (float*)d_out;            // [B, C, T]
  float* out_loss = outq + OUTQ;              // scalar
  float* out_idx  = outq + OUTQ + 1;          // [B, T] as float

  // 4MB swizzled-bf16 E scratch overlaid on outq (dead before vq_out writes)
  unsigned char* ebf = (unsigned char*)d_out;
  // small scratch in ws: idx (128KB) + partials (4KB)
  int*    idx     = (int*)d_ws;
  double* partial = (double*)((char*)d_ws + (size_t)N_ * sizeof(int));

  ebf_prep_kernel  <<<2048,     256, 0, stream>>>(emb, ebf);
  vq_argmin_kernel <<<N_ / BM,  256, 0, stream>>>(lat, emb, ebf, idx);
  vq_out_kernel    <<<512,      256, 0, stream>>>(lat, emb, idx, outq, partial);
  vq_loss_kernel   <<<1,        256, 0, stream>>>(partial, out_loss);
  vq_idxcopy_kernel<<<N_ / 256, 256, 0, stream>>>(idx, out_idx);
}

// Round 5
// 318.812 us; speedup vs baseline: 18.3175x; 1.1665x over previous
//
#include <hip/hip_runtime.h>

// Problem constants
#define B_ 16
#define C_ 256
#define T_ 2048
#define K_ 8192
#define D_ 256
#define N_ (B_ * T_)                 // 32768 rows
#define OUTQ ((size_t)B_ * C_ * T_)  // 8388608 quantized elements

#define BM 128                       // rows per argmin block
#define CHUNK 128                    // codes per LDS chunk (64KB)
#define NCHUNK (K_ / CHUNK)          // 64
#define NTHR 512                     // 8 waves: 2 row-groups x 4 code-groups
// Phase-1 margin (biased-mm units). Worst-case bf16 2*2^-9*||x||*||e|| <=1.77e-4
// + pack quant 6.1e-5 + fp32 bin slack 3.2e-5 = 2.7e-4 < 4e-4.
#define MARGINF 4e-4f
#define BIASF 0.03125f               // 2^-5, folded into MFMA acc init
#define QCAP 1024

typedef __attribute__((ext_vector_type(8))) short bf16x8;   // 8 bf16 = 4 VGPR
typedef __attribute__((ext_vector_type(4))) float f32x4;

__device__ __forceinline__ unsigned f2bf(float f) {         // RTNE f32->bf16
  unsigned u = __float_as_uint(f);
  return (u + 0x7FFFu + ((u >> 16) & 1u)) >> 16;
}
__device__ __forceinline__ unsigned umin_(unsigned a, unsigned b){return a<b?a:b;}
__device__ __forceinline__ unsigned umax_(unsigned a, unsigned b){return a>b?a:b;}

#define GLDS(g, l) __builtin_amdgcn_global_load_lds( \
    (const __attribute__((address_space(1))) void*)(g), \
    (__attribute__((address_space(3))) void*)(l), 16, 0, 0)

// ---------------------------------------------------------------------------
// Prep: E fp32 -> bf16, XOR-16 swizzle PRE-APPLIED in global memory so that
// global_load_lds (linear) lands it swizzled in LDS (T2 both-sides rule).
// Element (code,d) bf16 stored at byte: code*512 + ((2d) ^ ((code&15)<<4)).
// ---------------------------------------------------------------------------
__global__ __launch_bounds__(256) void ebf_prep_kernel(
    const float* __restrict__ emb, unsigned char* __restrict__ ebf)
{
  int gid  = blockIdx.x * 256 + threadIdx.x;    // 8192 codes x 64 quads
  int code = gid >> 6, dq = gid & 63;
  float4 v = *reinterpret_cast<const float4*>(emb + (size_t)code * D_ + dq * 4);
  unsigned lo = f2bf(v.x) | (f2bf(v.y) << 16);
  unsigned hi = f2bf(v.z) | (f2bf(v.w) << 16);
  unsigned off = code * 512 + ((dq * 8) ^ ((code & 15) << 4));
  *reinterpret_cast<uint2*>(ebf + off) = make_uint2(lo, hi);
}

// ---------------------------------------------------------------------------
// Argmin: phase 1 = bf16 MFMA GEMM (A=X rows resident in registers, B=E via
// swizzled global_load_lds dbuf), per-(lane,row-slot) top-2 of packed
// (quantized mm+BIAS | k). Phase 2 = exact fp32-rounding-emulated refine of
// all candidates within MARGINF of the row max, via load-balanced worklist.
// 8 waves (2 row-groups x 4 code-groups) -> 2 waves/SIMD for stall hiding.
// ---------------------------------------------------------------------------
__global__ __launch_bounds__(NTHR, 2) void vq_argmin_kernel(
    const float* __restrict__ lat, const float* __restrict__ emb,
    const unsigned char* __restrict__ ebf, int* __restrict__ idx_out,
    float* __restrict__ idxf_out)
{
  __shared__ __align__(16) unsigned char Ebuf[2][CHUNK * 512];  // 128KB dbuf
  __shared__ unsigned rmaxU[4][BM];
  __shared__ unsigned long long bestp[BM];
  __shared__ unsigned qlist[QCAP];
  __shared__ int qn;

  const int tid  = threadIdx.x;
  const int lane = tid & 63;
  const int w    = tid >> 6;       // wave 0..7
  const int rg   = w >> 2;         // row group (64 rows)
  const int cg   = w & 3;          // code group (32 codes of the 128-chunk)
  const int kg   = lane >> 4;      // k-group 0..3 (16x16x32 A/B k map)
  const int l15  = lane & 15;

  const int n0    = blockIdx.x * BM;
  const int bb    = n0 >> 11;                  // batch (BM | 2048)
  const int tbase = n0 & (T_ - 1);
  const float* latb = lat + (size_t)bb * C_ * T_;

  if (tid == 0) qn = 0;
  if (tid < BM) bestp[tid] = ~0ull;

  // prefetch chunk 0 (each wave DMAs its 8KB slice; lane*16 on SOURCE only)
  {
    const unsigned char* src = ebf + w * 8192 + lane * 16;
    unsigned char* dst = &Ebuf[0][w * 8192];
    #pragma unroll
    for (int j = 0; j < 8; ++j) GLDS(src + j * 1024, dst + j * 1024);
  }

  // ---- A fragments: 64 rows x 256 dims bf16, resident (128 VGPR) ----
  // A map: row = lane&15 (+rf*16+rg*64), k = (lane>>4)*8 + j (+ks*32)
  bf16x8 A[4][8];
  #pragma unroll
  for (int rf = 0; rf < 4; ++rf) {
    const int t = tbase + rg * 64 + rf * 16 + l15;
    const float* lp = latb + t;
    #pragma unroll
    for (int ks = 0; ks < 8; ++ks) {
      const int c0 = ks * 32 + kg * 8;
      bf16x8 a;
      #pragma unroll
      for (int j = 0; j < 8; ++j)
        a[j] = (short)f2bf(lp[(size_t)(c0 + j) * T_]);   // coalesced across l15
      A[rf][ks] = a;
    }
  }
  __syncthreads();   // drains chunk-0 DMA

  unsigned m1[16], m2[16];
  #pragma unroll
  for (int s = 0; s < 16; ++s) { m1[s] = 0u; m2[s] = 0u; }
  const unsigned kv0 = cg * 32 + l15;

  for (int ch = 0; ch < NCHUNK; ++ch) {
    const int pb = ch & 1;
    if (ch + 1 < NCHUNK) {       // prefetch next chunk into other buffer
      const unsigned char* src =
          ebf + (size_t)(ch + 1) * (CHUNK * 512) + w * 8192 + lane * 16;
      unsigned char* dst = &Ebuf[pb ^ 1][w * 8192];
      #pragma unroll
      for (int j = 0; j < 8; ++j) GLDS(src + j * 1024, dst + j * 1024);
    }

    // B fragments: col = lane&15, k = (lane>>4)*8+j — swizzled, conflict-free
    const unsigned char* bbase = &Ebuf[pb][0];
    #pragma unroll
    for (int cf = 0; cf < 2; ++cf) {
      const int code_l = cg * 32 + cf * 16 + l15;
      bf16x8 Bf[8];
      #pragma unroll
      for (int ks = 0; ks < 8; ++ks) {
        const unsigned off = code_l * 512 + ((ks * 64 + kg * 16) ^ (l15 << 4));
        Bf[ks] = *reinterpret_cast<const bf16x8*>(bbase + off);
      }
      const unsigned kv = kv0 + (unsigned)(ch * CHUNK + cf * 16);
      #pragma unroll
      for (int rf = 0; rf < 4; ++rf) {
        f32x4 acc = {BIASF, BIASF, BIASF, BIASF};   // BIAS folded into C-init
        #pragma unroll
        for (int ks = 0; ks < 8; ++ks)
          acc = __builtin_amdgcn_mfma_f32_16x16x32_bf16(A[rf][ks], Bf[ks],
                                                        acc, 0, 0, 0);
        #pragma unroll
        for (int r = 0; r < 4; ++r) {   // C: col=lane&15, row=(lane>>4)*4+r
          const unsigned p = (__float_as_uint(acc[r]) & 0xFFFFE000u) | kv;
          const int s = rf * 4 + r;
          const unsigned mn = umin_(p, m1[s]);
          m1[s] = umax_(p, m1[s]);
          m2[s] = umax_(m2[s], mn);
        }
      }
    }
    __syncthreads();   // drain DMA(ch+1), release Ebuf[pb]
  }

  // ---- row max: reduce over lane&15 (16 lanes hold same row set) ----
  #pragma unroll
  for (int s = 0; s < 16; ++s) {
    unsigned v = m1[s];
    v = umax_(v, __shfl_xor(v, 1));
    v = umax_(v, __shfl_xor(v, 2));
    v = umax_(v, __shfl_xor(v, 4));
    v = umax_(v, __shfl_xor(v, 8));
    const int row = rg * 64 + (s >> 2) * 16 + kg * 4 + (s & 3);
    rmaxU[cg][row] = v;                 // 16 lanes write same value: benign
  }
  __syncthreads();

  // ---- candidate emission (load-balanced worklist) ----
  #pragma unroll
  for (int s = 0; s < 16; ++s) {
    const int row = rg * 64 + (s >> 2) * 16 + kg * 4 + (s & 3);
    const unsigned rm = umax_(umax_(rmaxU[0][row], rmaxU[1][row]),
                              umax_(rmaxU[2][row], rmaxU[3][row]));
    const float thr = __uint_as_float(rm & 0xFFFFE000u) - MARGINF;
    #pragma unroll
    for (int which = 0; which < 2; ++which) {
      const unsigned m = which ? m2[s] : m1[s];
      if (__uint_as_float(m & 0xFFFFE000u) >= thr) {
        int id = atomicAdd(&qn, 1);
        if (id < QCAP) qlist[id] = ((unsigned)row << 13) | (m & 0x1FFFu);
      }
    }
  }
  __syncthreads();

  // ---- phase 2: exact refine, one candidate per lane ----
  const int nq = qn < QCAP ? qn : QCAP;
  for (int i = tid; i < nq; i += NTHR) {
    const unsigned e = qlist[i];
    const int row = (int)(e >> 13);
    const int k   = (int)(e & 0x1FFFu);
    const int t   = tbase + row;
    const float* xp = latb + t;
    const float* ep = emb + (size_t)k * D_;
    float x2 = 0.f, e2 = 0.f;
    double da = 0.0;
    {
      #pragma clang fp contract(off)
      for (int c = 0; c < D_; ++c) {
        const float xv = xp[(size_t)c * T_];
        const float ev = ep[c];
        const float xs = xv * xv; x2 = x2 + xs;   // sequential fp32, ref order
        const float es = ev * ev; e2 = e2 + es;
        da = fma((double)xv, (double)ev, da);
      }
    }
    float dist;
    {
      #pragma clang fp contract(off)
      const float mmf = (float)da;     // mm rounded to fp32
      const float tk  = x2 + e2;       // fl(x2 + e2)
      const float two = 2.0f * mmf;    // exact
      dist = tk - two;                 // final fp32 rounding
    }
    const unsigned long long pk =
        ((unsigned long long)__float_as_uint(dist) << 32) | (unsigned)k;
    atomicMin(&bestp[row], pk);        // first-index tie-break via low bits
  }
  __syncthreads();
  if (tid < BM) {
    const int k = (int)(bestp[tid] & 0xFFFFFFFFu);
    idx_out[n0 + tid]  = k;
    idxf_out[n0 + tid] = (float)k;     // float idx output folded in
  }
}

// ---------------------------------------------------------------------------
// Output gather + loss partials. Block = (b, 64-t chunk). The 64 needed emb
// rows are staged in LDS via fully-coalesced float4 reads (1KB bursts) into a
// [c][r] layout (+1 pad) so the write phase reads conflict-free; lat reads and
// outq writes stay coalesced over t.
// ---------------------------------------------------------------------------
__global__ __launch_bounds__(256) void vq_out_kernel(
    const float* __restrict__ lat, const float* __restrict__ emb,
    const int* __restrict__ idx, float* __restrict__ outq,
    double* __restrict__ partial)
{
  __shared__ float Ecol[256][65];      // [c][r], 66.6KB
  __shared__ double sred[256];
  const int gid = blockIdx.x;          // b(16) x tc(32)
  const int b   = gid >> 5;
  const int t0  = (gid & 31) * 64;

  // stage: 16 iters x 4 rows; r uniform per wave, c4 = lane
  {
    const int r4 = threadIdx.x >> 6, c4 = threadIdx.x & 63;
    for (int it = 0; it < 16; ++it) {
      const int r = it * 4 + r4;
      const int n = idx[b * T_ + t0 + r];
      const float4 v =
          *reinterpret_cast<const float4*>(emb + (size_t)n * D_ + c4 * 4);
      Ecol[c4 * 4 + 0][r] = v.x;
      Ecol[c4 * 4 + 1][r] = v.y;
      Ecol[c4 * 4 + 2][r] = v.z;
      Ecol[c4 * 4 + 3][r] = v.w;
    }
  }
  __syncthreads();

  const int cq = threadIdx.x >> 6, tl = threadIdx.x & 63;
  const int t  = t0 + tl;
  double lsum = 0.0;
  for (int ci = 0; ci < 64; ++ci) {
    const int c = cq * 64 + ci;
    const size_t off = ((size_t)b * C_ + c) * T_ + t;
    const float q = Ecol[c][tl];       // bank = (c + tl) % 32: conflict-free
    const float l = lat[off];
    outq[off] = q;
    const double d = (double)q - (double)l;
    lsum += d * d;
  }
  sred[threadIdx.x] = lsum;
  __syncthreads();
  for (int s = 128; s > 0; s >>= 1) {
    if (threadIdx.x < s) sred[threadIdx.x] += sred[threadIdx.x + s];
    __syncthreads();
  }
  if (threadIdx.x == 0) partial[gid] = sred[0];
}

__global__ __launch_bounds__(256) void vq_loss_kernel(
    const double* __restrict__ partial, float* __restrict__ out_loss)
{
  __shared__ double sred[256];
  double s = 0.0;
  for (int i = threadIdx.x; i < 512; i += 256) s += partial[i];
  sred[threadIdx.x] = s;
  __syncthreads();
  for (int st = 128; st > 0; st >>= 1) {
    if (threadIdx.x < st) sred[threadIdx.x] += sred[threadIdx.x + st];
    __syncthreads();
  }
  if (threadIdx.x == 0) {
    double m = sred[0] / (double)OUTQ;
    out_loss[0] = (float)(m + 0.25 * m);
  }
}

extern "C" void kernel_launch(void* const* d_in, const int* in_sizes, int n_in,
                              void* d_out, int out_size, void* d_ws, size_t ws_size,
                              hipStream_t stream)
{
  const float* lat = (const float*)d_in[0];   // [B, C, T] fp32
  const float* emb = (const float*)d_in[1];   // [K, D] fp32

  float* outq     = (float*)d_out;            // [B, C, T]
  float* out_loss = outq + OUTQ;              // scalar
  float* out_idx  = outq + OUTQ + 1;          // [B, T] as float

  // 4MB swizzled-bf16 E scratch overlaid on outq (dead before vq_out writes)
  unsigned char* ebf = (unsigned char*)d_out;
  // small scratch in ws: idx (128KB) + partials (4KB)
  int*    idx     = (int*)d_ws;
  double* partial = (double*)((char*)d_ws + (size_t)N_ * sizeof(int));

  ebf_prep_kernel  <<<2048,    256,  0, stream>>>(emb, ebf);
  vq_argmin_kernel <<<N_ / BM, NTHR, 0, stream>>>(lat, emb, ebf, idx, out_idx);
  vq_out_kernel    <<<512,     256,  0, stream>>>(lat, emb, idx, outq, partial);
  vq_loss_kernel   <<<1,       256,  0, stream>>>(partial, out_loss);
}